// Round 4
// baseline (156.746 us; speedup 1.0000x reference)
//
#include <hip/hip_runtime.h>
#include <hip/hip_bf16.h>
#include <stdint.h>

// ZoeDepth attractor head. R3: split into two internally-uniform kernels.
//   zoed_mlp:  per-wave barrier-free MFMA MLP (x -> A), hid transposed via
//              per-wave private LDS (no __syncthreads at all).
//   zoed_attr: pure streaming attractor (bprev + A -> out, duplicated).

#define HW 16384
#define ALPHA 300.0f

typedef short bf16x8_t __attribute__((ext_vector_type(8)));
typedef float f32x4_t __attribute__((ext_vector_type(4)));

__device__ __forceinline__ unsigned short f2bf(float f) {
  unsigned int u = __builtin_bit_cast(unsigned int, f);
  u += 0x7fffu + ((u >> 16) & 1u);
  return (unsigned short)(u >> 16);
}
__device__ __forceinline__ unsigned int pack2(float a, float b) {
  return (unsigned int)f2bf(a) | ((unsigned int)f2bf(b) << 16);
}

// ---------------------------------------------------------------------------
// Prep: w1 (128x256) and w2 (16x128) fp32 -> bf16 blobs in plain frag layout.
// w1: [kc(8)][o(128)][c'(32)] shorts @0 (64 KiB).
// w2: [kc(4)][a(16)][o'(32)] shorts @short-offset 32768 (4 KiB).
// ---------------------------------------------------------------------------
__global__ void zoed_prep(const float* __restrict__ w1,
                          const float* __restrict__ w2,
                          unsigned short* __restrict__ blob) {
  int i = blockIdx.x * 256 + threadIdx.x;  // 136*256 = 34816 = 32768 + 2048
  if (i < 32768) {
    int o = i >> 8, c = i & 255;
    blob[(c >> 5) * 4096 + o * 32 + (c & 31)] = f2bf(w1[i]);
  } else {
    int i2 = i - 32768;
    int a = i2 >> 7, o = i2 & 127;
    blob[32768 + (o >> 5) * 512 + a * 32 + (o & 31)] = f2bf(w2[i2]);
  }
}

// ---------------------------------------------------------------------------
// MLP kernel: A[n][16][HW] = softplus(w2 @ relu(w1 @ x + b1) + b2).
// One wave = 16 pixels, fully independent. Grid 1024 x 256thr (4 waves/blk).
// ---------------------------------------------------------------------------
__global__ __launch_bounds__(256, 4) void zoed_mlp(
    const float* __restrict__ x, const float* __restrict__ b1,
    const float* __restrict__ b2, const unsigned short* __restrict__ wblob,
    float* __restrict__ A) {
  __shared__ __align__(16) char smem[16384];  // 4 KiB private per wave
  const int t = threadIdx.x;
  const int lane = t & 63;
  const int l15 = lane & 15;   // pixel-in-group / M-row
  const int quad = lane >> 4;  // k-subgroup
  const int wv = t >> 6;
  char* hb = smem + wv * 4096;  // per-wave hid buffer [px(16)][o(128)] bf16

  const int wid = blockIdx.x * 4 + wv;
  const int px0 = wid * 16;  // global pixel 0..65535
  const int n = px0 >> 14;
  const int p = px0 & 16383;

  // ---- preload all 64 x values (8 k-chunks x 8 ch) ----
  const float* xb = x + (size_t)(n * 256 + quad * 8) * HW + p + l15;
  float xr[8][8];
#pragma unroll
  for (int kc = 0; kc < 8; kc++)
#pragma unroll
    for (int j = 0; j < 8; j++) xr[kc][j] = xb[(size_t)(kc * 32 + j) * HW];

  f32x4_t acc[8];
#pragma unroll
  for (int m = 0; m < 8; m++) acc[m] = (f32x4_t){0.f, 0.f, 0.f, 0.f};

  // ---- GEMM1: 8 k-chunks x 8 M-tiles, weights direct from L2-hot blob ----
  const char* wb1 = (const char*)wblob + l15 * 64 + quad * 16;
#pragma unroll
  for (int kc = 0; kc < 8; kc++) {
    bf16x8_t bfrag;
    unsigned int* bu = (unsigned int*)&bfrag;
    bu[0] = pack2(xr[kc][0], xr[kc][1]);
    bu[1] = pack2(xr[kc][2], xr[kc][3]);
    bu[2] = pack2(xr[kc][4], xr[kc][5]);
    bu[3] = pack2(xr[kc][6], xr[kc][7]);
#pragma unroll
    for (int m = 0; m < 8; m++) {
      bf16x8_t af = *(const bf16x8_t*)(wb1 + kc * 8192 + m * 1024);
      acc[m] = __builtin_amdgcn_mfma_f32_16x16x32_bf16(af, bfrag, acc[m], 0, 0, 0);
    }
  }

  // ---- hid: relu(acc + b1) -> bf16 -> per-wave LDS, layout [px][o] with
  //      16B-granule XOR swizzle by (px&3). C-frag: (o=m*16+quad*4+r, px=l15)
#pragma unroll
  for (int m = 0; m < 8; m++) {
    f32x4_t b1v = *(const f32x4_t*)(b1 + m * 16 + quad * 4);
    f32x4_t h = acc[m] + b1v;
    h[0] = fmaxf(h[0], 0.f);
    h[1] = fmaxf(h[1], 0.f);
    h[2] = fmaxf(h[2], 0.f);
    h[3] = fmaxf(h[3], 0.f);
    int G = m * 2 + (quad >> 1);  // 16B granule index (o0 = m*16+quad*4)
    unsigned int* dst = (unsigned int*)(hb + l15 * 256 + ((G ^ (l15 & 3)) << 4) +
                                        (quad & 1) * 8);
    dst[0] = pack2(h[0], h[1]);
    dst[1] = pack2(h[2], h[3]);
  }
  // same-wave LDS round trip: no barrier needed (lgkmcnt only)

  // ---- GEMM2: softplus(w2 @ hid + b2) ----
  f32x4_t acc2 = (f32x4_t){0.f, 0.f, 0.f, 0.f};
  const char* wb2 = (const char*)wblob + 65536 + l15 * 64 + quad * 16;
#pragma unroll
  for (int kc2 = 0; kc2 < 4; kc2++) {
    bf16x8_t a2 = *(const bf16x8_t*)(wb2 + kc2 * 1024);
    int G = kc2 * 4 + quad;  // o-granule for (o = kc2*32 + quad*8)
    bf16x8_t bh = *(const bf16x8_t*)(hb + l15 * 256 + ((G ^ (l15 & 3)) << 4));
    acc2 = __builtin_amdgcn_mfma_f32_16x16x32_bf16(a2, bh, acc2, 0, 0, 0);
  }
  f32x4_t b2v = *(const f32x4_t*)(b2 + quad * 4);
  float* Ab = A + (size_t)(n * 16 + quad * 4) * HW + p + l15;
#pragma unroll
  for (int r = 0; r < 4; r++) {
    float zz = acc2[r] + b2v[r];
    float sp = fmaxf(zz, 0.f) + log1pf(__expf(-fabsf(zz)));  // stable softplus
    Ab[(size_t)r * HW] = sp;
  }
}

// ---------------------------------------------------------------------------
// Attractor kernel: out = bprev + sum_a exp(-alpha*dx^2)*dx, duplicated.
// Thread = (pixel, 16-bin group). Grid 1024 x 256thr.
// ---------------------------------------------------------------------------
__global__ __launch_bounds__(256, 4) void zoed_attr(
    const float* __restrict__ bprev, const float* __restrict__ A,
    float* __restrict__ out) {
  const int t = threadIdx.x;
  const int blk = blockIdx.x;
  const int P = (blk & 255) * 256 + t;  // 0..65535
  const int bg = blk >> 8;              // bin group 0..3
  const int n = P >> 14;
  const int p = P & 16383;

  // pre-issue all loads: 16 A + 16 bprev
  const float* Ab = A + (size_t)(n * 16) * HW + p;
  float Av[16];
#pragma unroll
  for (int a = 0; a < 16; a++) Av[a] = Ab[(size_t)a * HW];

  size_t obase = (size_t)(n * 64 + bg * 16) * HW + p;
  const float* bp = bprev + obase;
  float bpr[16];
#pragma unroll
  for (int b = 0; b < 16; b++) bpr[b] = bp[(size_t)b * HW];

  float* o1 = out + obase;
  float* o2 = out + (size_t)(4 * 64) * HW + obase;
#pragma unroll
  for (int b = 0; b < 16; b++) {
    float c = bpr[b];
    float d0 = 0.f, d1 = 0.f;
#pragma unroll
    for (int a = 0; a < 8; a++) {
      float dx = Av[a] - c;
      float e = __expf(dx * dx * -ALPHA);
      d0 = fmaf(e, dx, d0);
    }
#pragma unroll
    for (int a = 8; a < 16; a++) {
      float dx = Av[a] - c;
      float e = __expf(dx * dx * -ALPHA);
      d1 = fmaf(e, dx, d1);
    }
    float r = c + (d0 + d1);
    __builtin_nontemporal_store(r, o1 + (size_t)b * HW);
    __builtin_nontemporal_store(r, o2 + (size_t)b * HW);
  }
}

extern "C" void kernel_launch(void* const* d_in, const int* in_sizes, int n_in,
                              void* d_out, int out_size, void* d_ws,
                              size_t ws_size, hipStream_t stream) {
  const float* x = (const float*)d_in[0];      // 4*256*128*128
  const float* bprev = (const float*)d_in[1];  // 4*64*128*128
  const float* w1 = (const float*)d_in[2];     // 128*256
  const float* b1 = (const float*)d_in[3];     // 128
  const float* w2 = (const float*)d_in[4];     // 16*128
  const float* b2 = (const float*)d_in[5];     // 16
  float* outp = (float*)d_out;                 // 2 * 4194304

  unsigned short* blob = (unsigned short*)d_ws;           // 69632 B
  float* Abuf = (float*)((char*)d_ws + (1 << 20));        // 4 MiB @ +1 MiB

  zoed_prep<<<136, 256, 0, stream>>>(w1, w2, blob);
  zoed_mlp<<<1024, 256, 0, stream>>>(x, b1, b2, blob, Abuf);
  zoed_attr<<<1024, 256, 0, stream>>>(bprev, Abuf, outp);
}

// Round 6
// 147.355 us; speedup vs baseline: 1.0637x; 1.0637x over previous
//
#include <hip/hip_runtime.h>
#include <hip/hip_bf16.h>
#include <stdint.h>

// ZoeDepth attractor head. R5: LDS-DMA GEMM1 pipeline with EXPLICIT vmcnt
// waits (R4's barrier-free ring raced: compiler emits no DMA->ds_read wait).
// sched_barrier(0) fences pin every VMEM op inside its iteration so the
// hand-computed vmcnt counts are exact. Attractor = R3-proven version.

#define HW 16384
#define ALPHA 300.0f

typedef short bf16x8_t __attribute__((ext_vector_type(8)));
typedef float f32x4_t __attribute__((ext_vector_type(4)));

// s_waitcnt with vmcnt=N only (lgkmcnt=15, expcnt=7 untouched); gfx9 layout:
// vmcnt[3:0]=imm[3:0], vmcnt[5:4]=imm[15:14], expcnt=imm[6:4], lgkm=imm[11:8]
#define WAIT_VM(N) \
  __builtin_amdgcn_s_waitcnt(((N)&0xF) | 0x70 | 0xF00 | (((N) >> 4) << 14))
#define SB() __builtin_amdgcn_sched_barrier(0)

__device__ __forceinline__ unsigned short f2bf(float f) {
  unsigned int u = __builtin_bit_cast(unsigned int, f);
  u += 0x7fffu + ((u >> 16) & 1u);
  return (unsigned short)(u >> 16);
}
__device__ __forceinline__ unsigned int pack2(float a, float b) {
  return (unsigned int)f2bf(a) | ((unsigned int)f2bf(b) << 16);
}
// async global->LDS, 16B/lane; LDS dest = wave-uniform base + lane*16
__device__ __forceinline__ void lds_dma16(const float* g, char* l) {
  __builtin_amdgcn_global_load_lds(
      (const __attribute__((address_space(1))) unsigned int*)g,
      (__attribute__((address_space(3))) unsigned int*)l, 16, 0, 0);
}

// ---------------------------------------------------------------------------
// Prep: w1 (128x256) and w2 (16x128) fp32 -> bf16 blobs in frag layout.
// w1: [kc(8)][o(128)][c'(32)] shorts @0 (64 KiB).
// w2: [kc(4)][a(16)][o'(32)] shorts @byte 65536 (4 KiB).
// ---------------------------------------------------------------------------
__global__ void zoed_prep(const float* __restrict__ w1,
                          const float* __restrict__ w2,
                          unsigned short* __restrict__ blob) {
  int i = blockIdx.x * 256 + threadIdx.x;  // 136*256 = 34816 = 32768 + 2048
  if (i < 32768) {
    int o = i >> 8, c = i & 255;
    blob[(c >> 5) * 4096 + o * 32 + (c & 31)] = f2bf(w1[i]);
  } else {
    int i2 = i - 32768;
    int a = i2 >> 7, o = i2 & 127;
    blob[32768 + (o >> 5) * 512 + a * 32 + (o & 31)] = f2bf(w2[i2]);
  }
}

// ---------------------------------------------------------------------------
// GEMM1 pipeline step. Ring slot = KC&3 (2 KiB: c_local 0..15 @0, 16..31
// @1024; float at c_local*64 + px*4). WN = exact vmcnt threshold proving
// this chunk's DMA pair completed (see derivation in session notes).
// ---------------------------------------------------------------------------
template <int KC, int WN>
__device__ __forceinline__ void g1_step(const char* xl, const char* wb1,
                                        const float* xg, char* wbase,
                                        f32x4_t (&acc)[8]) {
  WAIT_VM(WN);
  SB();
  const char* xs = xl + (KC & 3) * 2048;
  float xv[8];
#pragma unroll
  for (int j = 0; j < 8; j++) xv[j] = *(const float*)(xs + j * 64);
  bf16x8_t bfrag;
  unsigned int* bu = (unsigned int*)&bfrag;
  bu[0] = pack2(xv[0], xv[1]);
  bu[1] = pack2(xv[2], xv[3]);
  bu[2] = pack2(xv[4], xv[5]);
  bu[3] = pack2(xv[6], xv[7]);
  SB();  // pin: ds_reads above, refill below
  if constexpr (KC < 4) {
    lds_dma16(xg + (size_t)((KC + 4) * 32) * HW, wbase + (KC & 3) * 2048);
    lds_dma16(xg + (size_t)((KC + 4) * 32 + 16) * HW,
              wbase + (KC & 3) * 2048 + 1024);
  }
  bf16x8_t af[8];
#pragma unroll
  for (int m = 0; m < 8; m++)
    af[m] = *(const bf16x8_t*)(wb1 + KC * 8192 + m * 1024);
  SB();  // pin af loads before the next iteration's WAIT_VM
#pragma unroll
  for (int m = 0; m < 8; m++)
    acc[m] = __builtin_amdgcn_mfma_f32_16x16x32_bf16(af[m], bfrag, acc[m],
                                                     0, 0, 0);
}

// ---------------------------------------------------------------------------
// MLP: A[n][16][HW] = softplus(w2 @ relu(w1 @ x + b1) + b2).
// Wave = 16 px, barrier-free. Per-wave LDS 8 KiB = 4-slot x-ring; hid (4 KiB)
// overlays slots 0-1 after GEMM1. Grid 1024 x 256 (16 waves/CU, 1 generation).
// ---------------------------------------------------------------------------
__global__ __launch_bounds__(256, 4) void zoed_mlp(
    const float* __restrict__ x, const float* __restrict__ b1,
    const float* __restrict__ b2, const unsigned short* __restrict__ wblob,
    float* __restrict__ A) {
  __shared__ __align__(16) char smem[32768];
  const int t = threadIdx.x;
  const int lane = t & 63;
  const int l15 = lane & 15;
  const int quad = lane >> 4;
  const int wv = t >> 6;
  char* wbase = smem + wv * 8192;

  const int wid = blockIdx.x * 4 + wv;
  const int n = wid >> 10;
  const int p = (wid << 4) & 16383;

  // DMA source: lane = (c_sub = lane>>2, px_grp = lane&3), 16B per lane
  const float* xg =
      x + (size_t)(n * 256 + (lane >> 2)) * HW + p + (lane & 3) * 4;

  // preloop: chunks 0..3 -> slots 0..3 (pairs P0..P3, 8 VMEM ops)
#pragma unroll
  for (int kc = 0; kc < 4; kc++) {
    lds_dma16(xg + (size_t)(kc * 32) * HW, wbase + kc * 2048);
    lds_dma16(xg + (size_t)(kc * 32 + 16) * HW, wbase + kc * 2048 + 1024);
  }

  f32x4_t acc[8];
#pragma unroll
  for (int m = 0; m < 8; m++) acc[m] = (f32x4_t){0.f, 0.f, 0.f, 0.f};

  const char* wb1 = (const char*)wblob + l15 * 64 + quad * 16;
  const char* xl = wbase + (quad >> 1) * 1024 + (quad & 1) * 512 + l15 * 4;

  // Exact newer-op counts vs this chunk's DMA pair (pairs + af, SB-pinned):
  g1_step<0, 6>(xl, wb1, xg, wbase, acc);
  g1_step<1, 14>(xl, wb1, xg, wbase, acc);
  g1_step<2, 22>(xl, wb1, xg, wbase, acc);
  g1_step<3, 30>(xl, wb1, xg, wbase, acc);
  g1_step<4, 38>(xl, wb1, xg, wbase, acc);
  g1_step<5, 36>(xl, wb1, xg, wbase, acc);
  g1_step<6, 34>(xl, wb1, xg, wbase, acc);
  g1_step<7, 32>(xl, wb1, xg, wbase, acc);

  // ---- hid: relu(acc+b1) -> bf16 -> per-wave LDS (overlays slots 0-1);
  //      same-wave DS ops are in-order, no barrier needed ----
  char* hb = wbase;
#pragma unroll
  for (int m = 0; m < 8; m++) {
    f32x4_t b1v = *(const f32x4_t*)(b1 + m * 16 + quad * 4);
    f32x4_t h = acc[m] + b1v;
    h[0] = fmaxf(h[0], 0.f);
    h[1] = fmaxf(h[1], 0.f);
    h[2] = fmaxf(h[2], 0.f);
    h[3] = fmaxf(h[3], 0.f);
    int G = m * 2 + (quad >> 1);
    unsigned int* dst = (unsigned int*)(hb + l15 * 256 +
                                        ((G ^ (l15 & 3)) << 4) + (quad & 1) * 8);
    dst[0] = pack2(h[0], h[1]);
    dst[1] = pack2(h[2], h[3]);
  }

  // ---- GEMM2: softplus(w2 @ hid + b2) ----
  f32x4_t acc2 = (f32x4_t){0.f, 0.f, 0.f, 0.f};
  const char* wb2 = (const char*)wblob + 65536 + l15 * 64 + quad * 16;
#pragma unroll
  for (int kc2 = 0; kc2 < 4; kc2++) {
    bf16x8_t a2 = *(const bf16x8_t*)(wb2 + kc2 * 1024);
    int G = kc2 * 4 + quad;
    bf16x8_t bh = *(const bf16x8_t*)(hb + l15 * 256 + ((G ^ (l15 & 3)) << 4));
    acc2 = __builtin_amdgcn_mfma_f32_16x16x32_bf16(a2, bh, acc2, 0, 0, 0);
  }
  f32x4_t b2v = *(const f32x4_t*)(b2 + quad * 4);
  float* Ab = A + (size_t)(n * 16 + quad * 4) * HW + p + l15;
#pragma unroll
  for (int r = 0; r < 4; r++) {
    float zz = acc2[r] + b2v[r];
    float sp = fmaxf(zz, 0.f) + log1pf(__expf(-fabsf(zz)));  // stable softplus
    Ab[(size_t)r * HW] = sp;
  }
}

// ---------------------------------------------------------------------------
// Attractor (R3-proven): out = bprev + sum_a exp(-alpha*dx^2)*dx, duplicated.
// Thread = (pixel, 16-bin group). Grid 1024 x 256.
// ---------------------------------------------------------------------------
__global__ __launch_bounds__(256, 4) void zoed_attr(
    const float* __restrict__ bprev, const float* __restrict__ A,
    float* __restrict__ out) {
  const int t = threadIdx.x;
  const int blk = blockIdx.x;
  const int P = (blk & 255) * 256 + t;  // 0..65535
  const int bg = blk >> 8;              // bin group 0..3
  const int n = P >> 14;
  const int p = P & 16383;

  const float* Ab = A + (size_t)(n * 16) * HW + p;
  float Av[16];
#pragma unroll
  for (int a = 0; a < 16; a++) Av[a] = Ab[(size_t)a * HW];

  size_t obase = (size_t)(n * 64 + bg * 16) * HW + p;
  const float* bp = bprev + obase;
  float bpr[16];
#pragma unroll
  for (int b = 0; b < 16; b++) bpr[b] = bp[(size_t)b * HW];

  float* o1 = out + obase;
  float* o2 = out + (size_t)(4 * 64) * HW + obase;
#pragma unroll
  for (int b = 0; b < 16; b++) {
    float c = bpr[b];
    float d0 = 0.f, d1 = 0.f;
#pragma unroll
    for (int a = 0; a < 8; a++) {
      float dx = Av[a] - c;
      float e = __expf(dx * dx * -ALPHA);
      d0 = fmaf(e, dx, d0);
    }
#pragma unroll
    for (int a = 8; a < 16; a++) {
      float dx = Av[a] - c;
      float e = __expf(dx * dx * -ALPHA);
      d1 = fmaf(e, dx, d1);
    }
    float r = c + (d0 + d1);
    __builtin_nontemporal_store(r, o1 + (size_t)b * HW);
    __builtin_nontemporal_store(r, o2 + (size_t)b * HW);
  }
}

extern "C" void kernel_launch(void* const* d_in, const int* in_sizes, int n_in,
                              void* d_out, int out_size, void* d_ws,
                              size_t ws_size, hipStream_t stream) {
  const float* x = (const float*)d_in[0];      // 4*256*128*128
  const float* bprev = (const float*)d_in[1];  // 4*64*128*128
  const float* w1 = (const float*)d_in[2];     // 128*256
  const float* b1 = (const float*)d_in[3];     // 128
  const float* w2 = (const float*)d_in[4];     // 16*128
  const float* b2 = (const float*)d_in[5];     // 16
  float* outp = (float*)d_out;                 // 2 * 4194304

  unsigned short* blob = (unsigned short*)d_ws;     // 69632 B
  float* Abuf = (float*)((char*)d_ws + (1 << 20));  // 4 MiB @ +1 MiB

  zoed_prep<<<136, 256, 0, stream>>>(w1, w2, blob);
  zoed_mlp<<<1024, 256, 0, stream>>>(x, b1, b2, blob, Abuf);
  zoed_attr<<<1024, 256, 0, stream>>>(bprev, Abuf, outp);
}